// Round 4
// baseline (870.315 us; speedup 1.0000x reference)
//
#include <hip/hip_runtime.h>

// Problem constants
#define BB    16384   // batch
#define PP    32      // obs dim
#define MCC   16      // control dim
#define HH    24
#define MM    64
#define LL    129           // history length
#define YROW  (LL*PP)       // 4128 floats per batch row
#define KK    (128*PP)      // 4096 contraction length (delays 0..127)

// ---------------------------------------------------------------------------
// Setup: build Wt[c][k], k = d*32+p, combining all four terms.
// grid 256 blocks (128 d x 2 c-halves), 256 threads.
// Identical math to the proven setup_k; only the final store is transposed
// (Wt[c*KK + k] instead of Wk[k*MCC + c]) -- still 32-float coalesced runs.
// ---------------------------------------------------------------------------
__global__ __launch_bounds__(256) void setup_k(
    const float* __restrict__ M0,  const float* __restrict__ Mt,
    const float* __restrict__ M0l, const float* __restrict__ Mb,
    const float* __restrict__ sig, const float* __restrict__ lam,
    const float* __restrict__ phi, const float* __restrict__ phit,
    float* __restrict__ Wt)
{
    __shared__ float sA[MM*HH];   // phi_tilde[j][i] * lambda[i]^0.25
    __shared__ float sB[MM*HH];   // phi[k][l]      * sigma[l]^0.25
    __shared__ float sWd[HH*HH];  // (lam*sig)^0.25 * conv at n=d-1

    const int t = threadIdx.x;
    const int d = blockIdx.x >> 1;
    const int h = blockIdx.x & 1;

#pragma unroll
    for (int r = 0; r < 6; ++r) {
        int e = t + r*256;            // 6*256 = 1536 = 64*24 exactly
        int col = e % HH;
        sA[e] = phit[e] * sqrtf(sqrtf(lam[col]));
        sB[e] = phi[e]  * sqrtf(sqrtf(sig[col]));
    }
    __syncthreads();

    if (d >= 1) {
        const int n  = d - 1;
        const int lo = n > 63 ? n - 63 : 0;
        const int hi = n < 63 ? n : 63;
        for (int e = t; e < HH*HH; e += 256) {
            int i = e / HH, l = e % HH;
            float s = 0.f;
            for (int j = lo; j <= hi; ++j) s += sA[j*HH + i] * sB[(n - j)*HH + l];
            sWd[e] = s;
        }
    }
    __syncthreads();

    const int c = h*8 + (t >> 5);
    const int p = t & 31;
    float wv = 0.f;
    if (d == 0) wv += M0[c*PP + p];
    if (d >= 1 && d <= MM) {
        const int j = d - 1;
#pragma unroll
        for (int i = 0; i < HH; ++i) wv += sA[j*HH + i] * Mt[(i*MCC + c)*PP + p];
    }
    if (d < MM) {
#pragma unroll
        for (int l = 0; l < HH; ++l) wv += sB[d*HH + l] * M0l[(l*MCC + c)*PP + p];
    }
    if (d >= 1) {
        const float* mb = Mb + h*256 + t;   // (c*32+p) == h*256 + t for t<256
#pragma unroll 16
        for (int e = 0; e < HH*HH; ++e) wv += sWd[e] * mb[e*512];
    }
    Wt[(size_t)c*KK + d*PP + p] = wv;
}

// ---------------------------------------------------------------------------
// Main: one thread per output element (row, c).
//   out[row][c] = sum_k Wt[c][k] * Y[row][k]
// 16 lanes share a row (y loads broadcast-coalesce); each lane streams its
// own contiguous Wt[c][*] (L2-resident, 256 KB total). No LDS, no barriers,
// no readlane -- every VALU op is a useful v_fmac. A/B double-buffered
// float4 loads, 8 in flight per wave.
// grid 1024 x 256 threads = 4 blocks/CU, 16 waves/CU.
// ---------------------------------------------------------------------------
#define LD(Y0,Y1,Y2,Y3,W0,W1,W2,W3,off)                                     \
    Y0 = *(const float4*)(yp + (off));      W0 = *(const float4*)(wp + (off));      \
    Y1 = *(const float4*)(yp + (off) + 4);  W1 = *(const float4*)(wp + (off) + 4);  \
    Y2 = *(const float4*)(yp + (off) + 8);  W2 = *(const float4*)(wp + (off) + 8);  \
    Y3 = *(const float4*)(yp + (off) + 12); W3 = *(const float4*)(wp + (off) + 12);

#define FMA4(Yv,Wv)                                                         \
    a0 = fmaf((Yv).x, (Wv).x, a0); a1 = fmaf((Yv).y, (Wv).y, a1);           \
    a2 = fmaf((Yv).z, (Wv).z, a2); a3 = fmaf((Yv).w, (Wv).w, a3);

__global__ __launch_bounds__(256, 4) void main_k(
    const float* __restrict__ Y, const float* __restrict__ Wt,
    float* __restrict__ out)
{
    const int t   = threadIdx.x;
    const int c   = t & 15;
    const int row = blockIdx.x * 16 + (t >> 4);

    const float* yp = Y  + (size_t)row * YROW;
    const float* wp = Wt + (size_t)c * KK;

    float a0 = 0.f, a1 = 0.f, a2 = 0.f, a3 = 0.f;
    float4 ya0, ya1, ya2, ya3, wa0, wa1, wa2, wa3;
    float4 yb0, yb1, yb2, yb3, wb0, wb1, wb2, wb3;

    LD(ya0, ya1, ya2, ya3, wa0, wa1, wa2, wa3, 0)

#pragma unroll 1
    for (int q = 0; q < KK; q += 32) {
        LD(yb0, yb1, yb2, yb3, wb0, wb1, wb2, wb3, q + 16)
        FMA4(ya0, wa0) FMA4(ya1, wa1) FMA4(ya2, wa2) FMA4(ya3, wa3)
        if (q + 32 < KK) {
            LD(ya0, ya1, ya2, ya3, wa0, wa1, wa2, wa3, q + 32)
        }
        FMA4(yb0, wb0) FMA4(yb1, wb1) FMA4(yb2, wb2) FMA4(yb3, wb3)
    }

    out[(size_t)row * MCC + c] = (a0 + a1) + (a2 + a3);
}

extern "C" void kernel_launch(void* const* d_in, const int* in_sizes, int n_in,
                              void* d_out, int out_size, void* d_ws, size_t ws_size,
                              hipStream_t stream) {
    (void)in_sizes; (void)n_in; (void)out_size; (void)ws_size;
    const float* y    = (const float*)d_in[0];
    const float* M0   = (const float*)d_in[1];
    const float* Mt   = (const float*)d_in[2];
    const float* M0l  = (const float*)d_in[3];
    const float* Mb   = (const float*)d_in[4];
    const float* sig  = (const float*)d_in[5];
    const float* lam  = (const float*)d_in[6];
    const float* phi  = (const float*)d_in[7];
    const float* phit = (const float*)d_in[8];

    float* Wt  = (float*)d_ws;          // 16*4096*4 = 256 KB scratch (transposed W)
    float* out = (float*)d_out;

    setup_k<<<256, 256, 0, stream>>>(M0, Mt, M0l, Mb, sig, lam, phi, phit, Wt);
    main_k<<<1024, 256, 0, stream>>>(y, Wt, out);
}

// Round 6
// 472.012 us; speedup vs baseline: 1.8438x; 1.8438x over previous
//
#include <hip/hip_runtime.h>

// Problem constants
#define BB    16384   // batch
#define PP    32      // obs dim
#define MCC   16      // control dim
#define HH    24
#define MM    64
#define LL    129           // history length
#define YROW  (LL*PP)       // 4128 floats per batch row
#define KK    (128*PP)      // 4096 contraction length (delays 0..127)

// Main-kernel tiling
#define ROWS   64           // batch rows per block (== lanes)
#define TPB    512          // 8 waves
#define STAGES 32
#define SK     128          // k per stage
#define BUFF   (ROWS*SK/4)  // 2048 float4 = 32 KB per buffer (double-buffered = 64 KB)

__device__ __forceinline__ float rl(float v, int lane) {
    return __int_as_float(__builtin_amdgcn_readlane(__float_as_int(v), lane));
}

// ---------------------------------------------------------------------------
// Setup: build Wk[k][c], k = d*32+p, combining all four terms.
// grid 256 blocks (128 d x 2 c-halves), 256 threads.  (unchanged, proven)
// ---------------------------------------------------------------------------
__global__ __launch_bounds__(256) void setup_k(
    const float* __restrict__ M0,  const float* __restrict__ Mt,
    const float* __restrict__ M0l, const float* __restrict__ Mb,
    const float* __restrict__ sig, const float* __restrict__ lam,
    const float* __restrict__ phi, const float* __restrict__ phit,
    float* __restrict__ Wk)
{
    __shared__ float sA[MM*HH];   // phi_tilde[j][i] * lambda[i]^0.25
    __shared__ float sB[MM*HH];   // phi[k][l]      * sigma[l]^0.25
    __shared__ float sWd[HH*HH];  // (lam*sig)^0.25 * conv at n=d-1

    const int t = threadIdx.x;
    const int d = blockIdx.x >> 1;
    const int h = blockIdx.x & 1;

#pragma unroll
    for (int r = 0; r < 6; ++r) {
        int e = t + r*256;            // 6*256 = 1536 = 64*24 exactly
        int col = e % HH;
        sA[e] = phit[e] * sqrtf(sqrtf(lam[col]));
        sB[e] = phi[e]  * sqrtf(sqrtf(sig[col]));
    }
    __syncthreads();

    if (d >= 1) {
        const int n  = d - 1;
        const int lo = n > 63 ? n - 63 : 0;
        const int hi = n < 63 ? n : 63;
        for (int e = t; e < HH*HH; e += 256) {
            int i = e / HH, l = e % HH;
            float s = 0.f;
            for (int j = lo; j <= hi; ++j) s += sA[j*HH + i] * sB[(n - j)*HH + l];
            sWd[e] = s;
        }
    }
    __syncthreads();

    const int c = h*8 + (t >> 5);
    const int p = t & 31;
    float wv = 0.f;
    if (d == 0) wv += M0[c*PP + p];
    if (d >= 1 && d <= MM) {
        const int j = d - 1;
#pragma unroll
        for (int i = 0; i < HH; ++i) wv += sA[j*HH + i] * Mt[(i*MCC + c)*PP + p];
    }
    if (d < MM) {
#pragma unroll
        for (int l = 0; l < HH; ++l) wv += sB[d*HH + l] * M0l[(l*MCC + c)*PP + p];
    }
    if (d >= 1) {
        const float* mb = Mb + h*256 + t;   // (c*32+p) == h*256 + t for t<256
#pragma unroll 16
        for (int e = 0; e < HH*HH; ++e) wv += sWd[e] * mb[e*512];
    }
    Wk[(d*PP + p)*MCC + c] = wv;
}

// 16 fmacs per k-step. Lane j+16*cg holds W[k=base+j][cg*4 .. cg*4+4).
#define FMASTEP(YV, J)                                                       \
    acc[0]  = fmaf(rl(Wc.x, (J)     ), (YV), acc[0]);                        \
    acc[1]  = fmaf(rl(Wc.y, (J)     ), (YV), acc[1]);                        \
    acc[2]  = fmaf(rl(Wc.z, (J)     ), (YV), acc[2]);                        \
    acc[3]  = fmaf(rl(Wc.w, (J)     ), (YV), acc[3]);                        \
    acc[4]  = fmaf(rl(Wc.x, (J) + 16), (YV), acc[4]);                        \
    acc[5]  = fmaf(rl(Wc.y, (J) + 16), (YV), acc[5]);                        \
    acc[6]  = fmaf(rl(Wc.z, (J) + 16), (YV), acc[6]);                        \
    acc[7]  = fmaf(rl(Wc.w, (J) + 16), (YV), acc[7]);                        \
    acc[8]  = fmaf(rl(Wc.x, (J) + 32), (YV), acc[8]);                        \
    acc[9]  = fmaf(rl(Wc.y, (J) + 32), (YV), acc[9]);                        \
    acc[10] = fmaf(rl(Wc.z, (J) + 32), (YV), acc[10]);                       \
    acc[11] = fmaf(rl(Wc.w, (J) + 32), (YV), acc[11]);                       \
    acc[12] = fmaf(rl(Wc.x, (J) + 48), (YV), acc[12]);                       \
    acc[13] = fmaf(rl(Wc.y, (J) + 48), (YV), acc[13]);                       \
    acc[14] = fmaf(rl(Wc.z, (J) + 48), (YV), acc[14]);                       \
    acc[15] = fmaf(rl(Wc.w, (J) + 48), (YV), acc[15]);

// ---------------------------------------------------------------------------
// Main: u[b,c] = sum_k Wk[k][c] * y[b][k], 256 blocks x 512 threads.
// Double-buffered LDS (2 x 32 KB, one barrier/stage), b128 XOR-swizzled
// layout, global loads issued pre-barrier so HBM latency hides under compute.
// Per stage: wave w owns 16 k; lane (kl=lane&15, cg=lane>>4) holds one
// float4 of W; broadcast via readlane with constant lane index.
// ---------------------------------------------------------------------------
__global__ __launch_bounds__(512) void main_k(
    const float* __restrict__ Y, const float* __restrict__ Wk,
    float* __restrict__ out)
{
    __shared__ float4 sY[2*BUFF];   // 65536 B total; reused for reduction

    const int t    = threadIdx.x;
    const int w    = t >> 6;          // wave 0..7
    const int lane = t & 63;
    const int blk  = blockIdx.x;

    // staging: thread -> (srow = t>>3, kq = t&7), 16 consecutive k each
    const int srow = t >> 3, kq = t & 7;
    const float* yst = Y + (size_t)(blk*ROWS + srow)*YROW + kq*16;
    const int wx = srow*32;           // float4-unit row base (32 float4/row)
    const int sx = srow & 7;          // XOR key for this row

    // compute: lane = row, wave w owns k_loc in [16w, 16w+16) each stage
    const int rbase4 = lane*32;
    const int rx     = lane & 7;

    // W fragment: lane holds Wk[(s*128 + w*16 + (lane&15))*16 + (lane>>4)*4 ..+4)
    const float* wst = Wk + ((w*16 + (lane & 15))*MCC + (lane >> 4)*4);

    float acc[16];
#pragma unroll
    for (int c = 0; c < 16; ++c) acc[c] = 0.f;

    float4 Yr[4], Wn, Wc;
    // prologue: stage 0 into registers, then into buf0
#pragma unroll
    for (int i = 0; i < 4; ++i) Yr[i] = *(const float4*)(yst + 4*i);
    Wn = *(const float4*)(wst);
#pragma unroll
    for (int i = 0; i < 4; ++i)
        sY[wx + ((kq*4 + i) ^ sx)] = Yr[i];

#pragma unroll 1
    for (int s = 0; s < STAGES; ++s) {
        const int cur = s & 1;

        Wc = Wn;
        if (s < STAGES - 1) {
            const float* yp = yst + (s + 1)*SK;
#pragma unroll
            for (int i = 0; i < 4; ++i) Yr[i] = *(const float4*)(yp + 4*i);
            Wn = *(const float4*)(wst + (size_t)(s + 1)*SK*MCC);
        }

        __syncthreads();   // buf[cur] fully written; all readers done with buf[cur^1]

        const float4* yb = &sY[cur*BUFF];
#pragma unroll
        for (int j4 = 0; j4 < 4; ++j4) {
            float4 y4 = yb[rbase4 + ((w*4 + j4) ^ rx)];
            FMASTEP(y4.x, j4*4 + 0)
            FMASTEP(y4.y, j4*4 + 1)
            FMASTEP(y4.z, j4*4 + 2)
            FMASTEP(y4.w, j4*4 + 3)
        }

        if (s < STAGES - 1) {
            float4* ob = &sY[(cur ^ 1)*BUFF];
#pragma unroll
            for (int i = 0; i < 4; ++i)
                ob[wx + ((kq*4 + i) ^ sx)] = Yr[i];
        }
    }

    // cross-wave reduction: 8 partials per (row, c)
    __syncthreads();
    float* red = (float*)sY;               // [t][16] = [(w*64+lane)][16], 32 KB
#pragma unroll
    for (int c = 0; c < 16; ++c) red[t*16 + c] = acc[c];
    __syncthreads();

    if (t < 256) {
        const int row = t >> 2, c4 = t & 3;
        float4 sum = make_float4(0.f, 0.f, 0.f, 0.f);
#pragma unroll
        for (int ww = 0; ww < 8; ++ww) {
            const float* rp = &red[(ww*64 + row)*16 + c4*4];
            sum.x += rp[0]; sum.y += rp[1]; sum.z += rp[2]; sum.w += rp[3];
        }
        *(float4*)(out + (size_t)(blk*ROWS + row)*MCC + c4*4) = sum;
    }
}

extern "C" void kernel_launch(void* const* d_in, const int* in_sizes, int n_in,
                              void* d_out, int out_size, void* d_ws, size_t ws_size,
                              hipStream_t stream) {
    (void)in_sizes; (void)n_in; (void)out_size; (void)ws_size;
    const float* y    = (const float*)d_in[0];
    const float* M0   = (const float*)d_in[1];
    const float* Mt   = (const float*)d_in[2];
    const float* M0l  = (const float*)d_in[3];
    const float* Mb   = (const float*)d_in[4];
    const float* sig  = (const float*)d_in[5];
    const float* lam  = (const float*)d_in[6];
    const float* phi  = (const float*)d_in[7];
    const float* phit = (const float*)d_in[8];

    float* Wk  = (float*)d_ws;          // 4096*16*4 = 256 KB scratch
    float* out = (float*)d_out;

    setup_k<<<256, 256, 0, stream>>>(M0, Mt, M0l, Mb, sig, lam, phi, phit, Wk);
    main_k<<<256, TPB, 0, stream>>>(y, Wk, out);
}

// Round 7
// 461.606 us; speedup vs baseline: 1.8854x; 1.0225x over previous
//
#include <hip/hip_runtime.h>

// Problem constants
#define BB    16384   // batch
#define PP    32      // obs dim
#define MCC   16      // control dim
#define HH    24
#define MM    64
#define LL    129           // history length
#define YROW  (LL*PP)       // 4128 floats per batch row
#define KK    (128*PP)      // 4096 contraction length (delays 0..127)

// Main-kernel tiling
#define ROWS   64           // batch rows per block (== lanes)
#define TPB    512          // 8 waves
#define STAGES 32
#define SK     128          // k per stage
#define BUF4   2048         // float4 slots per buffer = 32 KB (x2 = 64 KB total)

__device__ __forceinline__ float rl(float v, int lane) {
    return __int_as_float(__builtin_amdgcn_readlane(__float_as_int(v), lane));
}

// Direct global->LDS DMA, 16 B per lane. LDS dest = wave-uniform base + lane*16.
__device__ __forceinline__ void dma16(const float* g, float4* l) {
    __builtin_amdgcn_global_load_lds(
        (const __attribute__((address_space(1))) void*)g,
        (__attribute__((address_space(3))) void*)l, 16, 0, 0);
}

// ---------------------------------------------------------------------------
// Setup: build Wk[k][c], k = d*32+p, combining all four terms.
// grid 256 blocks (128 d x 2 c-halves), 256 threads.  (unchanged, proven)
// ---------------------------------------------------------------------------
__global__ __launch_bounds__(256) void setup_k(
    const float* __restrict__ M0,  const float* __restrict__ Mt,
    const float* __restrict__ M0l, const float* __restrict__ Mb,
    const float* __restrict__ sig, const float* __restrict__ lam,
    const float* __restrict__ phi, const float* __restrict__ phit,
    float* __restrict__ Wk)
{
    __shared__ float sA[MM*HH];   // phi_tilde[j][i] * lambda[i]^0.25
    __shared__ float sB[MM*HH];   // phi[k][l]      * sigma[l]^0.25
    __shared__ float sWd[HH*HH];  // (lam*sig)^0.25 * conv at n=d-1

    const int t = threadIdx.x;
    const int d = blockIdx.x >> 1;
    const int h = blockIdx.x & 1;

#pragma unroll
    for (int r = 0; r < 6; ++r) {
        int e = t + r*256;            // 6*256 = 1536 = 64*24 exactly
        int col = e % HH;
        sA[e] = phit[e] * sqrtf(sqrtf(lam[col]));
        sB[e] = phi[e]  * sqrtf(sqrtf(sig[col]));
    }
    __syncthreads();

    if (d >= 1) {
        const int n  = d - 1;
        const int lo = n > 63 ? n - 63 : 0;
        const int hi = n < 63 ? n : 63;
        for (int e = t; e < HH*HH; e += 256) {
            int i = e / HH, l = e % HH;
            float s = 0.f;
            for (int j = lo; j <= hi; ++j) s += sA[j*HH + i] * sB[(n - j)*HH + l];
            sWd[e] = s;
        }
    }
    __syncthreads();

    const int c = h*8 + (t >> 5);
    const int p = t & 31;
    float wv = 0.f;
    if (d == 0) wv += M0[c*PP + p];
    if (d >= 1 && d <= MM) {
        const int j = d - 1;
#pragma unroll
        for (int i = 0; i < HH; ++i) wv += sA[j*HH + i] * Mt[(i*MCC + c)*PP + p];
    }
    if (d < MM) {
#pragma unroll
        for (int l = 0; l < HH; ++l) wv += sB[d*HH + l] * M0l[(l*MCC + c)*PP + p];
    }
    if (d >= 1) {
        const float* mb = Mb + h*256 + t;   // (c*32+p) == h*256 + t for t<256
#pragma unroll 16
        for (int e = 0; e < HH*HH; ++e) wv += sWd[e] * mb[e*512];
    }
    Wk[(d*PP + p)*MCC + c] = wv;
}

// 16 fmacs per k-step. Lane J+16*cg holds W[k][cg*4 .. cg*4+4) in WV.
#define FMASTEP(WV, YV, J)                                              \
    acc[0]  = fmaf(rl((WV).x, (J)     ), (YV), acc[0]);                 \
    acc[1]  = fmaf(rl((WV).y, (J)     ), (YV), acc[1]);                 \
    acc[2]  = fmaf(rl((WV).z, (J)     ), (YV), acc[2]);                 \
    acc[3]  = fmaf(rl((WV).w, (J)     ), (YV), acc[3]);                 \
    acc[4]  = fmaf(rl((WV).x, (J) + 16), (YV), acc[4]);                 \
    acc[5]  = fmaf(rl((WV).y, (J) + 16), (YV), acc[5]);                 \
    acc[6]  = fmaf(rl((WV).z, (J) + 16), (YV), acc[6]);                 \
    acc[7]  = fmaf(rl((WV).w, (J) + 16), (YV), acc[7]);                 \
    acc[8]  = fmaf(rl((WV).x, (J) + 32), (YV), acc[8]);                 \
    acc[9]  = fmaf(rl((WV).y, (J) + 32), (YV), acc[9]);                 \
    acc[10] = fmaf(rl((WV).z, (J) + 32), (YV), acc[10]);                \
    acc[11] = fmaf(rl((WV).w, (J) + 32), (YV), acc[11]);                \
    acc[12] = fmaf(rl((WV).x, (J) + 48), (YV), acc[12]);                \
    acc[13] = fmaf(rl((WV).y, (J) + 48), (YV), acc[13]);                \
    acc[14] = fmaf(rl((WV).z, (J) + 48), (YV), acc[14]);                \
    acc[15] = fmaf(rl((WV).w, (J) + 48), (YV), acc[15]);

// One stage: 4 swizzled b128 LDS reads (phase-conflict-free), 16 k-steps.
#define STAGE_COMPUTE(YB, WV)                                           \
    {                                                                   \
        float4 y0 = (YB)[rbase + ((w4 + 0) ^ rx)];                      \
        float4 y1 = (YB)[rbase + ((w4 + 1) ^ rx)];                      \
        float4 y2 = (YB)[rbase + ((w4 + 2) ^ rx)];                      \
        float4 y3 = (YB)[rbase + ((w4 + 3) ^ rx)];                      \
        FMASTEP(WV, y0.x, 0)  FMASTEP(WV, y0.y, 1)                      \
        FMASTEP(WV, y0.z, 2)  FMASTEP(WV, y0.w, 3)                      \
        FMASTEP(WV, y1.x, 4)  FMASTEP(WV, y1.y, 5)                      \
        FMASTEP(WV, y1.z, 6)  FMASTEP(WV, y1.w, 7)                      \
        FMASTEP(WV, y2.x, 8)  FMASTEP(WV, y2.y, 9)                      \
        FMASTEP(WV, y2.z, 10) FMASTEP(WV, y2.w, 11)                     \
        FMASTEP(WV, y3.x, 12) FMASTEP(WV, y3.y, 13)                     \
        FMASTEP(WV, y3.z, 14) FMASTEP(WV, y3.w, 15)                     \
    }

// ---------------------------------------------------------------------------
// Main: u[b,c] = sum_k Wk[k][c] * y[b][k], 256 blocks x 512 threads.
// global_load_lds staging (no Yr registers, no ds_writes, no spills),
// double-buffered 2x32 KB LDS, raw s_barrier + counted vmcnt(5): one 5-op
// load slot {W, 4xDMA} per stage stays in flight across barriers.
// LDS layout (per stage, float4 units): slot m = row*32 + (k4 ^ (row&7)),
// achieved by pre-swizzling the per-lane GLOBAL source address (DMA dest
// is linear). Reader: lane=row reads k4 = w*4+j4 at m = row*32+(k4^(row&7)).
// ---------------------------------------------------------------------------
__global__ __launch_bounds__(512) void main_k(
    const float* __restrict__ Y, const float* __restrict__ Wk,
    float* __restrict__ out)
{
    __shared__ float4 sY[2*BUF4];   // 65536 B; reused (as float) for reduction

    const int t    = threadIdx.x;
    const int w    = t >> 6;          // wave 0..7
    const int lane = t & 63;
    const int blk  = blockIdx.x;

    // staging: wave w, call i covers LDS float4 slots m = w*256+i*64+lane.
    // row = m>>5 = w*8 + i*2 + (lane>>5); stored col k4 = (lane&31) ^ (row&7).
    const float* gsrc[4];
#pragma unroll
    for (int i = 0; i < 4; ++i) {
        const int row = w*8 + i*2 + (lane >> 5);
        const int col = (lane & 31) ^ (row & 7);
        gsrc[i] = Y + (size_t)(blk*ROWS + row)*YROW + col*4;
    }
    float4* const d0 = &sY[        w*256];   // buffer-0 dest base (uniform/wave)
    float4* const d1 = &sY[BUF4 + w*256];    // buffer-1 dest base

    // compute: lane = row; wave w owns k = w*16 .. w*16+16 each stage
    const int w4    = w*4;
    const int rbase = lane*32;
    const int rx    = lane & 7;

    // W fragment: lane (kl=lane&15, cg=lane>>4) holds W[s*128+w*16+kl][cg*4..+4)
    const float* wsrc = Wk + ((w*16 + (lane & 15))*MCC + (lane >> 4)*4);

    float acc[16];
#pragma unroll
    for (int c = 0; c < 16; ++c) acc[c] = 0.f;

    float4 Wa, Wb;
    const float4* buf0 = sY;
    const float4* buf1 = sY + BUF4;

    // prologue: slot(s=0) = {Wa, 4 DMA -> buf0}; slot(s=1) = {Wb, 4 DMA -> buf1}
    Wa = *(const float4*)(wsrc);
#pragma unroll
    for (int i = 0; i < 4; ++i) dma16(gsrc[i],      d0 + i*64);
    Wb = *(const float4*)(wsrc + SK*MCC);
#pragma unroll
    for (int i = 0; i < 4; ++i) dma16(gsrc[i] + SK, d1 + i*64);

#pragma unroll 1
    for (int sp = 0; sp < 16; ++sp) {
        // ---- even stage s = 2*sp : buf0, Wa ----
        asm volatile("s_waitcnt vmcnt(5)" ::: "memory");  // drain slot(2sp)
        __builtin_amdgcn_s_barrier();
        asm volatile("" ::: "memory");
        STAGE_COMPUTE(buf0, Wa)
        asm volatile("" ::: "memory");
        __builtin_amdgcn_s_barrier();                     // readers of buf0 done
        asm volatile("" ::: "memory");
        if (sp < 15) {
            const int sn = 2*sp + 2;                      // refill buf0
            Wa = *(const float4*)(wsrc + (size_t)sn*SK*MCC);
#pragma unroll
            for (int i = 0; i < 4; ++i) dma16(gsrc[i] + sn*SK, d0 + i*64);
        }

        // ---- odd stage s = 2*sp+1 : buf1, Wb ----
        if (sp == 15) asm volatile("s_waitcnt vmcnt(0)" ::: "memory");
        else          asm volatile("s_waitcnt vmcnt(5)" ::: "memory");
        __builtin_amdgcn_s_barrier();
        asm volatile("" ::: "memory");
        STAGE_COMPUTE(buf1, Wb)
        asm volatile("" ::: "memory");
        __builtin_amdgcn_s_barrier();                     // readers of buf1 done
        asm volatile("" ::: "memory");
        if (sp < 15) {
            const int sn = 2*sp + 3;                      // refill buf1
            Wb = *(const float4*)(wsrc + (size_t)sn*SK*MCC);
#pragma unroll
            for (int i = 0; i < 4; ++i) dma16(gsrc[i] + sn*SK, d1 + i*64);
        }
    }

    // cross-wave reduction: 8 partials per (row, c); pad 17 to spread banks
    __syncthreads();
    float* red = (float*)sY;               // 512*17*4 = 34816 B <= 65536
#pragma unroll
    for (int c = 0; c < 16; ++c) red[t*17 + c] = acc[c];
    __syncthreads();

    if (t < 256) {
        const int row = t >> 2, c4 = t & 3;
        float4 sum = make_float4(0.f, 0.f, 0.f, 0.f);
#pragma unroll
        for (int ww = 0; ww < 8; ++ww) {
            const float* rp = &red[(ww*64 + row)*17 + c4*4];
            sum.x += rp[0]; sum.y += rp[1]; sum.z += rp[2]; sum.w += rp[3];
        }
        *(float4*)(out + (size_t)(blk*ROWS + row)*MCC + c4*4) = sum;
    }
}

extern "C" void kernel_launch(void* const* d_in, const int* in_sizes, int n_in,
                              void* d_out, int out_size, void* d_ws, size_t ws_size,
                              hipStream_t stream) {
    (void)in_sizes; (void)n_in; (void)out_size; (void)ws_size;
    const float* y    = (const float*)d_in[0];
    const float* M0   = (const float*)d_in[1];
    const float* Mt   = (const float*)d_in[2];
    const float* M0l  = (const float*)d_in[3];
    const float* Mb   = (const float*)d_in[4];
    const float* sig  = (const float*)d_in[5];
    const float* lam  = (const float*)d_in[6];
    const float* phi  = (const float*)d_in[7];
    const float* phit = (const float*)d_in[8];

    float* Wk  = (float*)d_ws;          // 4096*16*4 = 256 KB scratch
    float* out = (float*)d_out;

    setup_k<<<256, 256, 0, stream>>>(M0, Mt, M0l, Mb, sig, lam, phi, phit, Wk);
    main_k<<<256, TPB, 0, stream>>>(y, Wk, out);
}

// Round 8
// 425.684 us; speedup vs baseline: 2.0445x; 1.0844x over previous
//
#include <hip/hip_runtime.h>

// Problem constants
#define BB    16384
#define PP    32
#define MCC   16
#define HH    24
#define MM    64
#define LL    129
#define YROW  (LL*PP)       // 4128 floats per batch row
#define KK    4096          // contraction length

// Main-kernel tiling
#define RB    32            // batch rows per main block
#define TPB   512           // 8 waves
#define NST   32            // stages
#define SK    128           // k per stage
#define BUF4  1024          // float4 slots per stage buffer (32 rows x 32 f4 = 16 KB)

typedef __attribute__((ext_vector_type(8))) _Float16 half8;
typedef __attribute__((ext_vector_type(4))) float    f32x4;

// Direct global->LDS DMA, 16 B per lane. Dest = wave-uniform base + lane*16.
__device__ __forceinline__ void dma16(const float* g, float4* l) {
    __builtin_amdgcn_global_load_lds(
        (const __attribute__((address_space(1))) void*)g,
        (__attribute__((address_space(3))) void*)l, 16, 0, 0);
}

// ---------------------------------------------------------------------------
// Setup: build Wk[k][c], k = d*32+p, combining all four terms. (proven)
// ---------------------------------------------------------------------------
__global__ __launch_bounds__(256) void setup_k(
    const float* __restrict__ M0,  const float* __restrict__ Mt,
    const float* __restrict__ M0l, const float* __restrict__ Mb,
    const float* __restrict__ sig, const float* __restrict__ lam,
    const float* __restrict__ phi, const float* __restrict__ phit,
    float* __restrict__ Wk)
{
    __shared__ float sA[MM*HH];
    __shared__ float sB[MM*HH];
    __shared__ float sWd[HH*HH];

    const int t = threadIdx.x;
    const int d = blockIdx.x >> 1;
    const int h = blockIdx.x & 1;

#pragma unroll
    for (int r = 0; r < 6; ++r) {
        int e = t + r*256;
        int col = e % HH;
        sA[e] = phit[e] * sqrtf(sqrtf(lam[col]));
        sB[e] = phi[e]  * sqrtf(sqrtf(sig[col]));
    }
    __syncthreads();

    if (d >= 1) {
        const int n  = d - 1;
        const int lo = n > 63 ? n - 63 : 0;
        const int hi = n < 63 ? n : 63;
        for (int e = t; e < HH*HH; e += 256) {
            int i = e / HH, l = e % HH;
            float s = 0.f;
            for (int j = lo; j <= hi; ++j) s += sA[j*HH + i] * sB[(n - j)*HH + l];
            sWd[e] = s;
        }
    }
    __syncthreads();

    const int c = h*8 + (t >> 5);
    const int p = t & 31;
    float wv = 0.f;
    if (d == 0) wv += M0[c*PP + p];
    if (d >= 1 && d <= MM) {
        const int j = d - 1;
#pragma unroll
        for (int i = 0; i < HH; ++i) wv += sA[j*HH + i] * Mt[(i*MCC + c)*PP + p];
    }
    if (d < MM) {
#pragma unroll
        for (int l = 0; l < HH; ++l) wv += sB[d*HH + l] * M0l[(l*MCC + c)*PP + p];
    }
    if (d >= 1) {
        const float* mb = Mb + h*256 + t;
#pragma unroll 16
        for (int e = 0; e < HH*HH; ++e) wv += sWd[e] * mb[e*512];
    }
    Wk[(d*PP + p)*MCC + c] = wv;
}

// ---------------------------------------------------------------------------
// Pack W into fp16 3-way-split B-fragments (exact decomposition).
// B-frag slot (kb, lane, j) := W[kb*32 + (lane>>4)*8 + j][lane&15]
// (the (laneGrp,j)->k rule just has to match the A-side -- bijection argument).
// ---------------------------------------------------------------------------
__global__ __launch_bounds__(512) void pack_k(
    const float* __restrict__ Wk,
    _Float16* __restrict__ Bh, _Float16* __restrict__ Bm, _Float16* __restrict__ Bl)
{
    const int kb = blockIdx.x;            // 0..127
    const int t  = threadIdx.x;           // 0..511
    const int l  = t >> 3, j = t & 7;
    const int k  = kb*32 + (l >> 4)*8 + j;
    const int c  = l & 15;
    const float v = Wk[k*MCC + c];
    const _Float16 h  = (_Float16)v;
    const float    r1 = v - (float)h;      // exact
    const _Float16 m  = (_Float16)r1;
    const float    r2 = r1 - (float)m;     // exact
    const _Float16 lo = (_Float16)r2;
    const int idx = kb*512 + l*8 + j;
    Bh[idx] = h; Bm[idx] = m; Bl[idx] = lo;
}

// ---------------------------------------------------------------------------
// Main: out[r][c] = sum_k Y[r][k] * W[k][c] via fp16-split MFMA.
// grid 512 x 512 threads (2 blocks/CU). Per block: 32 rows, full k.
// 8 waves: rt = w&1 (row 16-tile), kh = w>>2.. = w>>1 (k-quarter of stage).
// Stage: DMA 16 KB Y (pre-swizzled source, linear LDS dest), dbl-buffered.
// Each wave per stage: 1 k32-block: A = y rows (3 frags via exact fp16
// split), B = packed frags from L2, 6 MFMAs into one f32x4 acc.
// Epilogue: 4 kh-partials reduced via LDS, fixed order (deterministic).
// ---------------------------------------------------------------------------
__global__ __launch_bounds__(512, 4) void main_k(
    const float* __restrict__ Y,
    const half8* __restrict__ Bh, const half8* __restrict__ Bm,
    const half8* __restrict__ Bl,
    float* __restrict__ out)
{
    __shared__ float4 sY[2*BUF4];   // 32 KB

    const int t    = threadIdx.x;
    const int w    = t >> 6;
    const int lane = t & 63;
    const int blk  = blockIdx.x;

    // ---- staging: thread t covers f4 slots m = t and m = t+512 ----
    // slot m: row = m>>5, stored col c4 = m&31 holds global f4-col (c4 ^ (row&7))
    const int r0 = t >> 5;               // 0..15
    const int c4 = t & 31;
    const float* g0 = Y + (size_t)(blk*RB + r0     )*YROW + ((c4 ^ (r0 & 7))*4);
    const float* g1 = Y + (size_t)(blk*RB + r0 + 16)*YROW + ((c4 ^ (r0 & 7))*4); // (r0+16)&7 == r0&7
    // wave-uniform LDS dest bases (hardware adds lane*16B)
    float4* const dA0 = &sY[       w*64];        // slots w*64 + lane        (i=0)
    float4* const dA1 = &sY[512  + w*64];        // slots 512 + w*64 + lane  (i=1)
    float4* const dB0 = &sY[BUF4       + w*64];
    float4* const dB1 = &sY[BUF4 + 512 + w*64];

    // ---- compute mapping ----
    const int rt = w & 1;                // row tile (16 rows)
    const int kh = w >> 1;               // k-quarter within stage (0..3)
    const int rloc = lane & 15;
    const int o    = lane >> 4;          // k-octet group 0..3
    const int r    = rt*16 + rloc;
    const int rx   = r & 7;
    const int f0   = kh*8 + o*2;         // stage-local f4 index of j=0..3
    const int s0   = r*32 + ( f0      ^ rx);
    const int s1   = r*32 + ((f0 + 1) ^ rx);

    f32x4 acc = {0.f, 0.f, 0.f, 0.f};

    // prologue: stage 0 -> buffer 0
    dma16(g0, dA0);
    dma16(g1, dA1);

#pragma unroll 1
    for (int s = 0; s < NST; ++s) {
        __syncthreads();   // drains vmcnt: stage-s DMA complete; all readers past buf[other]

        if (s + 1 < NST) {             // prefetch stage s+1 into the other buffer
            const float* p0 = g0 + (s + 1)*SK;
            const float* p1 = g1 + (s + 1)*SK;
            if ((s + 1) & 1) { dma16(p0, dB0); dma16(p1, dB1); }
            else             { dma16(p0, dA0); dma16(p1, dA1); }
        }

        // ---- compute stage s from buf[s&1] (overlaps s+1 DMA) ----
        const float4* yb = &sY[(s & 1) ? BUF4 : 0];
        const float4 y0 = yb[s0];
        const float4 y1 = yb[s1];
        const float ya[8] = {y0.x, y0.y, y0.z, y0.w, y1.x, y1.y, y1.z, y1.w};

        half8 ah, am, al;
#pragma unroll
        for (int j = 0; j < 8; ++j) {
            const float v  = ya[j];
            const _Float16 hh = (_Float16)v;
            const float    q1 = v - (float)hh;    // exact
            const _Float16 mm = (_Float16)q1;
            const float    q2 = q1 - (float)mm;   // exact
            ah[j] = hh; am[j] = mm; al[j] = (_Float16)q2;
        }

        const int bi = (s*4 + kh)*64 + lane;
        const half8 bh = Bh[bi];
        const half8 bm = Bm[bi];
        const half8 bl = Bl[bi];

        acc = __builtin_amdgcn_mfma_f32_16x16x32_f16(ah, bh, acc, 0, 0, 0);
        acc = __builtin_amdgcn_mfma_f32_16x16x32_f16(ah, bm, acc, 0, 0, 0);
        acc = __builtin_amdgcn_mfma_f32_16x16x32_f16(am, bh, acc, 0, 0, 0);
        acc = __builtin_amdgcn_mfma_f32_16x16x32_f16(ah, bl, acc, 0, 0, 0);
        acc = __builtin_amdgcn_mfma_f32_16x16x32_f16(am, bm, acc, 0, 0, 0);
        acc = __builtin_amdgcn_mfma_f32_16x16x32_f16(al, bh, acc, 0, 0, 0);
    }

    // ---- epilogue: reduce 4 kh-partials per (row,c) ----
    __syncthreads();
    float* red = (float*)sY;                     // 512*4*4 = 8 KB
#pragma unroll
    for (int i = 0; i < 4; ++i) red[(w*64 + lane)*4 + i] = acc[i];
    __syncthreads();

    {
        // C/D layout (m89-verified): col = lane&15, row = (lane>>4)*4 + reg
        const int orow = t >> 4;                 // 0..31
        const int oc   = t & 15;
        const int ort  = orow >> 4, orl = orow & 15;
        const int ol   = (orl >> 2)*16 + oc;
        const int oreg = orl & 3;
        float ssum = 0.f;
#pragma unroll
        for (int q = 0; q < 4; ++q)              // fixed kh order -> deterministic
            ssum += red[((q*2 + ort)*64 + ol)*4 + oreg];
        out[(size_t)(blk*RB + orow)*MCC + oc] = ssum;
    }
}

extern "C" void kernel_launch(void* const* d_in, const int* in_sizes, int n_in,
                              void* d_out, int out_size, void* d_ws, size_t ws_size,
                              hipStream_t stream) {
    (void)in_sizes; (void)n_in; (void)out_size; (void)ws_size;
    const float* y    = (const float*)d_in[0];
    const float* M0   = (const float*)d_in[1];
    const float* Mt   = (const float*)d_in[2];
    const float* M0l  = (const float*)d_in[3];
    const float* Mb   = (const float*)d_in[4];
    const float* sig  = (const float*)d_in[5];
    const float* lam  = (const float*)d_in[6];
    const float* phi  = (const float*)d_in[7];
    const float* phit = (const float*)d_in[8];

    float*    Wk = (float*)d_ws;                    // 4096*16*4   = 256 KB
    _Float16* Bh = (_Float16*)(Wk + KK*MCC);        // 65536 halfs = 128 KB
    _Float16* Bm = Bh + KK*MCC;
    _Float16* Bl = Bm + KK*MCC;
    float*   out = (float*)d_out;

    setup_k<<<256, 256, 0, stream>>>(M0, Mt, M0l, Mb, sig, lam, phi, phit, Wk);
    pack_k <<<128, 512, 0, stream>>>(Wk, Bh, Bm, Bl);
    main_k <<<512, TPB, 0, stream>>>(y, (const half8*)Bh, (const half8*)Bm,
                                     (const half8*)Bl, out);
}

// Round 9
// 419.255 us; speedup vs baseline: 2.0759x; 1.0153x over previous
//
#include <hip/hip_runtime.h>

// Problem constants
#define BB    16384
#define PP    32
#define MCC   16
#define HH    24
#define MM    64
#define LL    129
#define YROW  (LL*PP)       // 4128 floats per batch row
#define KK    4096          // contraction length

// Main-kernel tiling
#define RB    32            // batch rows per main block
#define TPB   512           // 8 waves
#define NST   32            // stages
#define SK    128           // k per stage
#define BUF4  1024          // float4 slots per stage buffer (32 rows x 32 f4 = 16 KB)

typedef __attribute__((ext_vector_type(8))) _Float16 half8;
typedef __attribute__((ext_vector_type(4))) float    f32x4;

// Direct global->LDS DMA, 16 B per lane. Dest = wave-uniform base + lane*16.
__device__ __forceinline__ void dma16(const float* g, float4* l) {
    __builtin_amdgcn_global_load_lds(
        (const __attribute__((address_space(1))) void*)g,
        (__attribute__((address_space(3))) void*)l, 16, 0, 0);
}

// ---------------------------------------------------------------------------
// Setup: build W[k][c] (all four terms) and store directly as fp16 3-way-split
// B-fragments (exact decomposition; pack_k merged in, no Wk round-trip).
// Fragment slot: k=(kb*32+q): idx = kb*512 + ((q>>3)*16 + c)*8 + (q&7).
// ---------------------------------------------------------------------------
__global__ __launch_bounds__(256) void setup_k(
    const float* __restrict__ M0,  const float* __restrict__ Mt,
    const float* __restrict__ M0l, const float* __restrict__ Mb,
    const float* __restrict__ sig, const float* __restrict__ lam,
    const float* __restrict__ phi, const float* __restrict__ phit,
    _Float16* __restrict__ Bh, _Float16* __restrict__ Bm,
    _Float16* __restrict__ Bl)
{
    __shared__ float sA[MM*HH];
    __shared__ float sB[MM*HH];
    __shared__ float sWd[HH*HH];

    const int t = threadIdx.x;
    const int d = blockIdx.x >> 1;
    const int h = blockIdx.x & 1;

#pragma unroll
    for (int r = 0; r < 6; ++r) {
        int e = t + r*256;
        int col = e % HH;
        sA[e] = phit[e] * sqrtf(sqrtf(lam[col]));
        sB[e] = phi[e]  * sqrtf(sqrtf(sig[col]));
    }
    __syncthreads();

    if (d >= 1) {
        const int n  = d - 1;
        const int lo = n > 63 ? n - 63 : 0;
        const int hi = n < 63 ? n : 63;
        for (int e = t; e < HH*HH; e += 256) {
            int i = e / HH, l = e % HH;
            float s = 0.f;
            for (int j = lo; j <= hi; ++j) s += sA[j*HH + i] * sB[(n - j)*HH + l];
            sWd[e] = s;
        }
    }
    __syncthreads();

    const int c = h*8 + (t >> 5);
    const int p = t & 31;
    float wv = 0.f;
    if (d == 0) wv += M0[c*PP + p];
    if (d >= 1 && d <= MM) {
        const int j = d - 1;
#pragma unroll
        for (int i = 0; i < HH; ++i) wv += sA[j*HH + i] * Mt[(i*MCC + c)*PP + p];
    }
    if (d < MM) {
#pragma unroll
        for (int l = 0; l < HH; ++l) wv += sB[d*HH + l] * M0l[(l*MCC + c)*PP + p];
    }
    if (d >= 1) {
        const float* mb = Mb + h*256 + t;
#pragma unroll 16
        for (int e = 0; e < HH*HH; ++e) wv += sWd[e] * mb[e*512];
    }

    // exact fp16 3-way split, store in fragment layout
    const int k   = d*PP + p;
    const int kb  = k >> 5, q = k & 31;
    const int idx = kb*512 + ((q >> 3)*16 + c)*8 + (q & 7);
    const _Float16 hh = (_Float16)wv;
    const float    r1 = wv - (float)hh;     // exact
    const _Float16 mm = (_Float16)r1;
    const float    r2 = r1 - (float)mm;     // exact
    Bh[idx] = hh; Bm[idx] = mm; Bl[idx] = (_Float16)r2;
}

// ---------------------------------------------------------------------------
// Main: out[r][c] = sum_k Y[r][k] * W[k][c] via fp16-split MFMA.
// grid 512 x 512 (2 blocks/CU). R8 compute/layout verbatim; pipeline fixed:
// 3 LDS buffers, DMA(s+2) issued in stage s, and B(s+1) register loads
// issued BEFORE DMA(s+2) so the compiler's B-use wait (vmcnt(7), FIFO)
// retires only {DMA(s), B(s)} and keeps {DMA(s+1), B(s+1), DMA(s+2)}
// in flight across barriers. Per-wave vm ops/stage = 2 DMA + 3 B = 5.
// Steady-state wait at stage top: vmcnt(5) (last stage: vmcnt(3)).
// ---------------------------------------------------------------------------
__global__ __launch_bounds__(512, 4) void main_k(
    const float* __restrict__ Y,
    const half8* __restrict__ Bh8, const half8* __restrict__ Bm8,
    const half8* __restrict__ Bl8,
    float* __restrict__ out)
{
    __shared__ float4 sY[3*BUF4];   // 48 KB; reused (as float) for reduction

    const int t    = threadIdx.x;
    const int w    = t >> 6;
    const int lane = t & 63;
    const int blk  = blockIdx.x;

    // staging: thread t covers f4 slots m = t (rows 0..15) and m = t+512 (rows 16..31)
    const int r0 = t >> 5;               // 0..15
    const int c4 = t & 31;
    const float* g0 = Y + (size_t)(blk*RB + r0     )*YROW + ((c4 ^ (r0 & 7))*4);
    const float* g1 = Y + (size_t)(blk*RB + r0 + 16)*YROW + ((c4 ^ (r0 & 7))*4);

    // compute mapping (R8 verbatim)
    const int rt = w & 1;
    const int kh = w >> 1;
    const int rloc = lane & 15;
    const int o    = lane >> 4;
    const int r    = rt*16 + rloc;
    const int rx   = r & 7;
    const int f0   = kh*8 + o*2;
    const int s0   = r*32 + ( f0      ^ rx);
    const int s1   = r*32 + ((f0 + 1) ^ rx);

    const half8* bh = Bh8 + kh*64 + lane;   // + s*256 per stage
    const half8* bm = Bm8 + kh*64 + lane;
    const half8* bl = Bl8 + kh*64 + lane;

    f32x4 acc = {0.f, 0.f, 0.f, 0.f};

    // ---- prologue: DMA(0) ; B(0) ; DMA(1)  -> queue [DMA0 2, B0 3, DMA1 2]
    {
        float4* d0 = &sY[w*64];
        dma16(g0, d0); dma16(g1, d0 + 512);
    }
    half8 cbh = bh[0], cbm = bm[0], cbl = bl[0];
    {
        float4* d1 = &sY[BUF4 + w*64];
        dma16(g0 + SK, d1); dma16(g1 + SK, d1 + 512);
    }
    half8 nbh, nbm, nbl;

#pragma unroll 1
    for (int s = 0; s < NST; ++s) {
        // stage top: require DMA(s) done; keep the rest in flight
        if (s < NST - 1) asm volatile("s_waitcnt vmcnt(5)" ::: "memory");
        else             asm volatile("s_waitcnt vmcnt(3)" ::: "memory");
        __builtin_amdgcn_s_barrier();
        asm volatile("" ::: "memory");

        // B(s+1) register loads FIRST (older than next DMA in the FIFO)
        if (s < NST - 1) {
            const int bi = (s + 1)*256;
            nbh = bh[bi]; nbm = bm[bi]; nbl = bl[bi];
        }
        asm volatile("" ::: "memory");

        // DMA(s+2) into buffer (s+2)%3 (its readers finished before this barrier)
        if (s < NST - 2) {
            float4* dd = &sY[((s + 2) % 3)*BUF4 + w*64];
            dma16(g0 + (s + 2)*SK, dd); dma16(g1 + (s + 2)*SK, dd + 512);
        }
        asm volatile("" ::: "memory");

        // compute stage s from buf[s%3]
        const float4* yb = &sY[(s % 3)*BUF4];
        const float4 y0 = yb[s0];
        const float4 y1 = yb[s1];
        const float ya[8] = {y0.x, y0.y, y0.z, y0.w, y1.x, y1.y, y1.z, y1.w};

        half8 ah, am, al;
#pragma unroll
        for (int j = 0; j < 8; ++j) {
            const float v  = ya[j];
            const _Float16 hh = (_Float16)v;
            const float    q1 = v - (float)hh;    // exact
            const _Float16 mm = (_Float16)q1;
            const float    q2 = q1 - (float)mm;   // exact
            ah[j] = hh; am[j] = mm; al[j] = (_Float16)q2;
        }

        acc = __builtin_amdgcn_mfma_f32_16x16x32_f16(ah, cbh, acc, 0, 0, 0);
        acc = __builtin_amdgcn_mfma_f32_16x16x32_f16(ah, cbm, acc, 0, 0, 0);
        acc = __builtin_amdgcn_mfma_f32_16x16x32_f16(am, cbh, acc, 0, 0, 0);
        acc = __builtin_amdgcn_mfma_f32_16x16x32_f16(ah, cbl, acc, 0, 0, 0);
        acc = __builtin_amdgcn_mfma_f32_16x16x32_f16(am, cbm, acc, 0, 0, 0);
        acc = __builtin_amdgcn_mfma_f32_16x16x32_f16(al, cbh, acc, 0, 0, 0);

        cbh = nbh; cbm = nbm; cbl = nbl;
    }

    // ---- epilogue: reduce 4 kh-partials per (row,c)  (R8 verbatim) ----
    __syncthreads();
    float* red = (float*)sY;
#pragma unroll
    for (int i = 0; i < 4; ++i) red[(w*64 + lane)*4 + i] = acc[i];
    __syncthreads();

    {
        const int orow = t >> 4;                 // 0..31
        const int oc   = t & 15;
        const int ort  = orow >> 4, orl = orow & 15;
        const int ol   = (orl >> 2)*16 + oc;
        const int oreg = orl & 3;
        float ssum = 0.f;
#pragma unroll
        for (int q = 0; q < 4; ++q)              // fixed kh order -> deterministic
            ssum += red[((q*2 + ort)*64 + ol)*4 + oreg];
        out[(size_t)(blk*RB + orow)*MCC + oc] = ssum;
    }
}

extern "C" void kernel_launch(void* const* d_in, const int* in_sizes, int n_in,
                              void* d_out, int out_size, void* d_ws, size_t ws_size,
                              hipStream_t stream) {
    (void)in_sizes; (void)n_in; (void)out_size; (void)ws_size;
    const float* y    = (const float*)d_in[0];
    const float* M0   = (const float*)d_in[1];
    const float* Mt   = (const float*)d_in[2];
    const float* M0l  = (const float*)d_in[3];
    const float* Mb   = (const float*)d_in[4];
    const float* sig  = (const float*)d_in[5];
    const float* lam  = (const float*)d_in[6];
    const float* phi  = (const float*)d_in[7];
    const float* phit = (const float*)d_in[8];

    _Float16* Bh = (_Float16*)d_ws;               // 65536 halfs = 128 KB each
    _Float16* Bm = Bh + KK*MCC;
    _Float16* Bl = Bm + KK*MCC;
    float*   out = (float*)d_out;

    setup_k<<<256, 256, 0, stream>>>(M0, Mt, M0l, Mb, sig, lam, phi, phit,
                                     Bh, Bm, Bl);
    main_k <<<512, TPB, 0, stream>>>(y, (const half8*)Bh, (const half8*)Bm,
                                     (const half8*)Bl, out);
}